// Round 10
// baseline (1514.753 us; speedup 1.0000x reference)
//
#include <hip/hip_runtime.h>
#include <math.h>
#include <stdint.h>

#define VOCAB 64
#define H 64
#define BB 256
#define LL 2048

typedef float v2f __attribute__((ext_vector_type(2)));

#define PIN(x)  asm volatile("" : "+v"(x))
#define PIN4(f) asm volatile("" : "+v"(f.x), "+v"(f.y), "+v"(f.z), "+v"(f.w))

// 64-lane wave sum via DPP (row_shr 1/2/4/8, row_bcast15, row_bcast31), then
// broadcast total from lane 63. All VALU-pipe, no LDS latency.
__device__ __forceinline__ float wave_sum_dpp(float x) {
  int t;
  float r = x;
  t = __builtin_amdgcn_update_dpp(0, __float_as_int(r), 0x111, 0xf, 0xf, true); r += __int_as_float(t);
  t = __builtin_amdgcn_update_dpp(0, __float_as_int(r), 0x112, 0xf, 0xf, true); r += __int_as_float(t);
  t = __builtin_amdgcn_update_dpp(0, __float_as_int(r), 0x114, 0xf, 0xf, true); r += __int_as_float(t);
  t = __builtin_amdgcn_update_dpp(0, __float_as_int(r), 0x118, 0xf, 0xf, true); r += __int_as_float(t);
  t = __builtin_amdgcn_update_dpp(0, __float_as_int(r), 0x142, 0xf, 0xf, true); r += __int_as_float(t);
  t = __builtin_amdgcn_update_dpp(0, __float_as_int(r), 0x143, 0xf, 0xf, true); r += __int_as_float(t);
  return __int_as_float(__builtin_amdgcn_readlane(__float_as_int(r), 63));
}

// Phase 1: hidden depends only on the token id -> precompute 64 hidden vectors.
__global__ __launch_bounds__(64, 1) void encode_kernel(
    const float* __restrict__ embed, const float* __restrict__ W1,
    const float* __restrict__ b1, const float* __restrict__ W2,
    const float* __restrict__ b2, const float* __restrict__ gamma,
    const float* __restrict__ beta, float* __restrict__ table,
    float* __restrict__ kkg) {
  const int c = blockIdx.x;
  const int j = threadIdx.x;
  __shared__ float hs[H];
  __shared__ float zs[2 * H];
  const float h = embed[c * H + j];
  hs[j] = h;
  __syncthreads();
  float z0 = b1[j], z1 = b1[j + H];
#pragma unroll 8
  for (int i = 0; i < H; ++i) {
    const float hi = hs[i];
    z0 = fmaf(hi, W1[i * 2 * H + j], z0);
    z1 = fmaf(hi, W1[i * 2 * H + j + H], z1);
  }
  z0 = fmaxf(z0, 0.f);
  z1 = fmaxf(z1, 0.f);
  zs[j] = z0;
  zs[j + H] = z1;
  __syncthreads();
  float ff = b2[j];
#pragma unroll 8
  for (int m = 0; m < 2 * H; ++m) ff = fmaf(zs[m], W2[m * H + j], ff);
  const float x = h + ff;
  const float mu = wave_sum_dpp(x) * (1.f / 64.f);
  const float d = x - mu;
  const float var = wave_sum_dpp(d * d) * (1.f / 64.f);
  const float y = d * (1.f / sqrtf(var + 1e-5f)) * gamma[j] + beta[j];
  table[c * H + j] = y;
  const float s2 = wave_sum_dpp(y * y);
  if (j == 0) kkg[c] = s2;
}

// Gather: materialize the per-step key stream. rows[b][t][:] = table[seq[b][t]],
// kks[b][t] = kkg[seq[b][t]]. Bulk-parallel, HBM-BW bound (~134 MB writes).
__global__ __launch_bounds__(256, 1) void gather_kernel(
    const int* __restrict__ seq, const float* __restrict__ table,
    const float* __restrict__ kkg, float* __restrict__ rows,
    float* __restrict__ kks) {
  const int b = blockIdx.x;
  const int tid = threadIdx.x;
  __shared__ int tk[LL];
  {
    const int4* ssrc = (const int4*)(seq + (long)b * LL);
    int4* sdst = (int4*)tk;
#pragma unroll
    for (int q = 0; q < 2; ++q) sdst[q * 256 + tid] = ssrc[q * 256 + tid];
  }
  __syncthreads();
  const int j = tid & 63;
  const int tq = tid >> 6;
  float* dstb = rows + (long)b * LL * H;
  float* kb = kks + (long)b * LL;
  for (int t = tq; t < LL; t += 4) {
    const int c = tk[t];
    dstb[(long)t * H + j] = table[c * H + j];
    if (j == 0) kb[t] = kkg[c];
  }
}

// One scan step (stream version). R = carried row k(c_t) (update row, loaded
// last step), X <- fresh row k(c_{t+1}) (dot row) from the LINEAR stream.
// Addresses are induction-variable-only -> the compiler hoists/pipelines
// these global loads across iterations (vmcnt), unlike LDS. Arithmetic is
// bit-identical to the passing rounds 2-5/9.
#define STEP(T_IDX, R, X)                                                    \
  {                                                                          \
    const long t2 = ((T_IDX) + 2 < LL) ? (T_IDX) + 2 : LL - 1;               \
    const float4* xp = (const float4*)(rb + (long)((T_IDX) + 1) * H);        \
    _Pragma("unroll")                                                        \
    for (int q = 0; q < 16; ++q) X[q] = xp[q];                               \
    const float scp = rb[t2 * H + lane];                                     \
    const float kkp = kb[t2];                                                \
    const float vp = (vpA.x + vpA.y) + (vpB.x + vpB.y);                      \
    const float dv = sc - vp / (kk + 1e-6f);                                 \
    const float aa = dv * (2.f * vp + dv * kk);                              \
    const float s = wave_sum_dpp(aa);                                        \
    const float dvg = s > 0.f ? dv : 0.f;                                    \
    wcount += s > 0.f ? 1.f : 0.f;                                           \
    const v2f dv2 = (v2f){dvg, dvg};                                         \
    v2f nA = (v2f){0.f, 0.f}, nB = (v2f){0.f, 0.f};                          \
    _Pragma("unroll")                                                        \
    for (int q = 0; q < 16; ++q) {                                           \
      const float4 kv4 = R[q];                                               \
      const float4 kn4 = X[q];                                               \
      const v2f kva = (v2f){kv4.x, kv4.y}, kvb = (v2f){kv4.z, kv4.w};        \
      const v2f kna = (v2f){kn4.x, kn4.y}, knb = (v2f){kn4.z, kn4.w};        \
      M2[2 * q]     = __builtin_elementwise_fma(dv2, kva, M2[2 * q]);        \
      M2[2 * q + 1] = __builtin_elementwise_fma(dv2, kvb, M2[2 * q + 1]);    \
      nA = __builtin_elementwise_fma(M2[2 * q],     kna, nA);                \
      nB = __builtin_elementwise_fma(M2[2 * q + 1], knb, nB);                \
    }                                                                        \
    vpA = nA; vpB = nB;                                                      \
    sc = scn; kk = kkn; scn = scp; kkn = kkp;                                \
  }

// Phase 2+3 (stream): one block = one wave = one batch. No LDS in the loop;
// all per-step data comes from the linear gathered stream.
__global__ __launch_bounds__(64, 1) void scan_kernel_stream(
    const float* __restrict__ rows, const float* __restrict__ kks,
    const float* __restrict__ Wr, const float* __restrict__ br,
    const float* __restrict__ Wo, const float* __restrict__ bo,
    float* __restrict__ out, float* __restrict__ counts) {
  const int b = blockIdx.x;
  const int lane = threadIdx.x;
  const float* rb = rows + (long)b * LL * H;
  const float* kb = kks + (long)b * LL;
  __shared__ float xv[H];

  v2f M2[32];
#pragma unroll
  for (int r = 0; r < 32; ++r) M2[r] = (v2f){0.f, 0.f};
  float wcount = 0.f;

  float4 RA[16], RB[16];
  {
    const float4* r0 = (const float4*)rb;
#pragma unroll
    for (int q = 0; q < 16; ++q) RA[q] = r0[q];
  }
  float sc = rb[lane], kk = kb[0];
  float scn = rb[H + lane], kkn = kb[1];
  v2f vpA = (v2f){0.f, 0.f}, vpB = (v2f){0.f, 0.f};  // M=0 -> vp(0)=0

  int t = 0;
  for (int it = 0; it < 1023; ++it) {  // 1023*2 = 2046 steps
    STEP(t, RA, RB); ++t;
    STEP(t, RB, RA); ++t;
  }
  STEP(t, RA, RB);                     // t = 2046; dot row = stream row 2047

  xv[lane] = (vpA.x + vpA.y) + (vpB.x + vpB.y);
  __syncthreads();
  float t1 = br[lane];
#pragma unroll 8
  for (int i = 0; i < H; ++i) t1 = fmaf(xv[i], Wr[i * H + lane], t1);
  __syncthreads();
  xv[lane] = t1;
  __syncthreads();
  float lg = bo[lane];
#pragma unroll 8
  for (int m = 0; m < H; ++m) lg = fmaf(xv[m], Wo[m * H + lane], lg);
  out[(long)b * H + lane] = lg;
  if (lane == 0) counts[b] = wcount;
}

// ---------- Fallback (round-5 kernel, used only if ws too small) ----------
#define STEPL(T_IDX, RU, RD, RP)                                             \
  {                                                                          \
    const int cp = cnn;                                                      \
    const int tpre = ((T_IDX) + 3 < LL) ? (T_IDX) + 3 : LL - 1;              \
    int cin = toks[tpre];                                                    \
    float scp = T[cp * H + lane];                                            \
    float kkp = KK[cp];                                                      \
    const float4* rp = (const float4*)(T + cp * H);                          \
    _Pragma("unroll")                                                        \
    for (int q = 0; q < 16; ++q) RP[q] = rp[q];                              \
    const float vp = (vpA.x + vpA.y) + (vpB.x + vpB.y);                      \
    const float dv = sc - vp / (kk + 1e-6f);                                 \
    const float aa = dv * (2.f * vp + dv * kk);                              \
    const float s = wave_sum_dpp(aa);                                        \
    const float dvg = s > 0.f ? dv : 0.f;                                    \
    wcount += s > 0.f ? 1.f : 0.f;                                           \
    const v2f dv2 = (v2f){dvg, dvg};                                         \
    v2f nA = (v2f){0.f, 0.f}, nB = (v2f){0.f, 0.f};                          \
    _Pragma("unroll")                                                        \
    for (int q = 0; q < 16; ++q) {                                           \
      const float4 kv4 = RU[q];                                              \
      const float4 kn4 = RD[q];                                              \
      const v2f kva = (v2f){kv4.x, kv4.y}, kvb = (v2f){kv4.z, kv4.w};        \
      const v2f kna = (v2f){kn4.x, kn4.y}, knb = (v2f){kn4.z, kn4.w};        \
      M2[2 * q]     = __builtin_elementwise_fma(dv2, kva, M2[2 * q]);        \
      M2[2 * q + 1] = __builtin_elementwise_fma(dv2, kvb, M2[2 * q + 1]);    \
      nA = __builtin_elementwise_fma(M2[2 * q],     kna, nA);                \
      nB = __builtin_elementwise_fma(M2[2 * q + 1], knb, nB);                \
    }                                                                        \
    vpA = nA; vpB = nB;                                                      \
    _Pragma("unroll")                                                        \
    for (int q = 0; q < 16; ++q) PIN4(RP[q]);                                \
    PIN(scp); PIN(kkp); PIN(cin);                                            \
    cn = cnn; cnn = cin;                                                     \
    sc = scn; kk = kkn; scn = scp; kkn = kkp;                                \
  }

__global__ __launch_bounds__(64, 1) void scan_kernel_lds(
    const int* __restrict__ seq, const float* __restrict__ table,
    const float* __restrict__ kkg, const float* __restrict__ Wr,
    const float* __restrict__ br, const float* __restrict__ Wo,
    const float* __restrict__ bo, float* __restrict__ out,
    float* __restrict__ counts) {
  const int b = blockIdx.x;
  const int lane = threadIdx.x;
  __shared__ float T[H * VOCAB];
  __shared__ float KK[VOCAB];
  __shared__ int toks[LL];
  __shared__ float xv[H];
  {
    const float4* src = (const float4*)table;
    float4* dst = (float4*)T;
#pragma unroll
    for (int q = 0; q < 16; ++q) dst[q * 64 + lane] = src[q * 64 + lane];
    KK[lane] = kkg[lane];
    const int4* ssrc = (const int4*)(seq + (long)b * LL);
    int4* sdst = (int4*)toks;
#pragma unroll
    for (int q = 0; q < 8; ++q) sdst[q * 64 + lane] = ssrc[q * 64 + lane];
  }
  __syncthreads();
  v2f M2[32];
#pragma unroll
  for (int r = 0; r < 32; ++r) M2[r] = (v2f){0.f, 0.f};
  float wcount = 0.f;
  float4 RA[16], RB[16], RC[16];
  const int c0 = toks[0];
  int cn = toks[1], cnn = toks[2];
  float sc = T[c0 * H + lane], kk = KK[c0];
  float scn = T[cn * H + lane], kkn = KK[cn];
  {
    const float4* r0 = (const float4*)(T + c0 * H);
    const float4* r1 = (const float4*)(T + cn * H);
#pragma unroll
    for (int q = 0; q < 16; ++q) { RA[q] = r0[q]; RB[q] = r1[q]; }
#pragma unroll
    for (int q = 0; q < 16; ++q) { PIN4(RA[q]); PIN4(RB[q]); }
  }
  v2f vpA = (v2f){0.f, 0.f}, vpB = (v2f){0.f, 0.f};
  int t = 0;
  for (int it = 0; it < 682; ++it) {
    STEPL(t, RA, RB, RC); ++t;
    STEPL(t, RB, RC, RA); ++t;
    STEPL(t, RC, RA, RB); ++t;
  }
  STEPL(t, RA, RB, RC);
  xv[lane] = (vpA.x + vpA.y) + (vpB.x + vpB.y);
  __syncthreads();
  float t1 = br[lane];
#pragma unroll 8
  for (int i = 0; i < H; ++i) t1 = fmaf(xv[i], Wr[i * H + lane], t1);
  __syncthreads();
  xv[lane] = t1;
  __syncthreads();
  float lg = bo[lane];
#pragma unroll 8
  for (int m = 0; m < H; ++m) lg = fmaf(xv[m], Wo[m * H + lane], lg);
  out[(long)b * H + lane] = lg;
  if (lane == 0) counts[b] = wcount;
}

__global__ __launch_bounds__(256, 1) void finalize_kernel(const float* __restrict__ counts,
                                                          float* __restrict__ out) {
  const int lane = threadIdx.x;
  __shared__ float sbuf[BB];
  sbuf[lane] = counts[lane];
  __syncthreads();
  for (int off = BB / 2; off > 0; off >>= 1) {
    if (lane < off) sbuf[lane] += sbuf[lane + off];
    __syncthreads();
  }
  if (lane == 0) out[BB * H] = sbuf[0] / (float)(BB * (LL - 1));
}

extern "C" void kernel_launch(void* const* d_in, const int* in_sizes, int n_in,
                              void* d_out, int out_size, void* d_ws, size_t ws_size,
                              hipStream_t stream) {
  const int* seq      = (const int*)d_in[0];
  const float* embed  = (const float*)d_in[1];
  const float* W1     = (const float*)d_in[2];
  const float* b1     = (const float*)d_in[3];
  const float* W2     = (const float*)d_in[4];
  const float* b2     = (const float*)d_in[5];
  const float* gamma  = (const float*)d_in[6];
  const float* beta   = (const float*)d_in[7];
  const float* Wr     = (const float*)d_in[8];
  const float* br     = (const float*)d_in[9];
  const float* Wo     = (const float*)d_in[10];
  const float* bo     = (const float*)d_in[11];
  float* out = (float*)d_out;

  float* ws = (float*)d_ws;
  float* table  = ws;                    // 4096 f32
  float* kkg    = table + VOCAB * H;     // 64 f32
  float* counts = kkg + VOCAB;           // 256 f32
  float* rows   = ws + 8192;             // BB*LL*H f32 = 134 MB
  float* kks    = rows + (size_t)BB * LL * H;  // BB*LL f32 = 2 MB
  const size_t need = (8192 + (size_t)BB * LL * H + (size_t)BB * LL) * sizeof(float);

  encode_kernel<<<VOCAB, H, 0, stream>>>(embed, W1, b1, W2, b2, gamma, beta, table, kkg);
  if (ws_size >= need) {
    gather_kernel<<<BB, 256, 0, stream>>>(seq, table, kkg, rows, kks);
    scan_kernel_stream<<<BB, H, 0, stream>>>(rows, kks, Wr, br, Wo, bo, out, counts);
  } else {
    scan_kernel_lds<<<BB, H, 0, stream>>>(seq, table, kkg, Wr, br, Wo, bo, out, counts);
  }
  finalize_kernel<<<1, BB, 0, stream>>>(counts, out);
}

// Round 11
// 828.410 us; speedup vs baseline: 1.8285x; 1.8285x over previous
//
#include <hip/hip_runtime.h>
#include <math.h>
#include <stdint.h>

#define VOCAB 64
#define H 64
#define BB 256
#define LL 2048

typedef float v2f __attribute__((ext_vector_type(2)));

#define PIN(x)  asm volatile("" : "+v"(x))
#define PIN4(f) asm volatile("" : "+v"(f.x), "+v"(f.y), "+v"(f.z), "+v"(f.w))

// Async global->LDS DMA, 16 B per lane. No dest VGPR -> the scheduler cannot
// sink/fold it; issue position is program order, completion tracked by vmcnt.
__device__ __forceinline__ void dma16(const float* g, float* l) {
  __builtin_amdgcn_global_load_lds(
      (const __attribute__((address_space(1))) uint32_t*)g,
      (__attribute__((address_space(3))) uint32_t*)l, 16, 0, 0);
}

// 64-lane wave sum via DPP (row_shr 1/2/4/8, row_bcast15, row_bcast31), then
// broadcast total from lane 63. All VALU-pipe, no LDS latency.
__device__ __forceinline__ float wave_sum_dpp(float x) {
  int t;
  float r = x;
  t = __builtin_amdgcn_update_dpp(0, __float_as_int(r), 0x111, 0xf, 0xf, true); r += __int_as_float(t);
  t = __builtin_amdgcn_update_dpp(0, __float_as_int(r), 0x112, 0xf, 0xf, true); r += __int_as_float(t);
  t = __builtin_amdgcn_update_dpp(0, __float_as_int(r), 0x114, 0xf, 0xf, true); r += __int_as_float(t);
  t = __builtin_amdgcn_update_dpp(0, __float_as_int(r), 0x118, 0xf, 0xf, true); r += __int_as_float(t);
  t = __builtin_amdgcn_update_dpp(0, __float_as_int(r), 0x142, 0xf, 0xf, true); r += __int_as_float(t);
  t = __builtin_amdgcn_update_dpp(0, __float_as_int(r), 0x143, 0xf, 0xf, true); r += __int_as_float(t);
  return __int_as_float(__builtin_amdgcn_readlane(__float_as_int(r), 63));
}

// Phase 1: hidden depends only on the token id -> precompute 64 hidden vectors.
__global__ __launch_bounds__(64, 1) void encode_kernel(
    const float* __restrict__ embed, const float* __restrict__ W1,
    const float* __restrict__ b1, const float* __restrict__ W2,
    const float* __restrict__ b2, const float* __restrict__ gamma,
    const float* __restrict__ beta, float* __restrict__ table,
    float* __restrict__ kkg) {
  const int c = blockIdx.x;
  const int j = threadIdx.x;
  __shared__ float hs[H];
  __shared__ float zs[2 * H];
  const float h = embed[c * H + j];
  hs[j] = h;
  __syncthreads();
  float z0 = b1[j], z1 = b1[j + H];
#pragma unroll 8
  for (int i = 0; i < H; ++i) {
    const float hi = hs[i];
    z0 = fmaf(hi, W1[i * 2 * H + j], z0);
    z1 = fmaf(hi, W1[i * 2 * H + j + H], z1);
  }
  z0 = fmaxf(z0, 0.f);
  z1 = fmaxf(z1, 0.f);
  zs[j] = z0;
  zs[j + H] = z1;
  __syncthreads();
  float ff = b2[j];
#pragma unroll 8
  for (int m = 0; m < 2 * H; ++m) ff = fmaf(zs[m], W2[m * H + j], ff);
  const float x = h + ff;
  const float mu = wave_sum_dpp(x) * (1.f / 64.f);
  const float d = x - mu;
  const float var = wave_sum_dpp(d * d) * (1.f / 64.f);
  const float y = d * (1.f / sqrtf(var + 1e-5f)) * gamma[j] + beta[j];
  table[c * H + j] = y;
  const float s2 = wave_sum_dpp(y * y);
  if (j == 0) kkg[c] = s2;
}

// Gather: materialize the per-step key stream. rows[b][t][:] = table[seq[b][t]],
// kks[b][t] = kkg[seq[b][t]]. Bulk-parallel, HBM-BW bound (~134 MB writes).
__global__ __launch_bounds__(256, 1) void gather_kernel(
    const int* __restrict__ seq, const float* __restrict__ table,
    const float* __restrict__ kkg, float* __restrict__ rows,
    float* __restrict__ kks) {
  const int b = blockIdx.x;
  const int tid = threadIdx.x;
  __shared__ int tk[LL];
  {
    const int4* ssrc = (const int4*)(seq + (long)b * LL);
    int4* sdst = (int4*)tk;
#pragma unroll
    for (int q = 0; q < 2; ++q) sdst[q * 256 + tid] = ssrc[q * 256 + tid];
  }
  __syncthreads();
  const int j = tid & 63;
  const int tq = tid >> 6;
  float* dstb = rows + (long)b * LL * H;
  float* kb = kks + (long)b * LL;
  for (int t = tq; t < LL; t += 4) {
    const int c = tk[t];
    dstb[(long)t * H + j] = table[c * H + j];
    if (j == 0) kb[t] = kkg[c];
  }
}

// One scan step (ring version). R = update row k_t (carried regs; if the
// compiler refolds it to LDS, the re-read is a cheap linear ring read).
// X <- dot row k_{t+1} from ring slot (t+1)&15. Scalars for t+2 prefetched.
// Arithmetic bit-identical to the passing rounds 2-5/8-10.
#define RSLOT(T_) (ring + (((T_) & 15) << 6))
#define STEP(T_IDX, R, X)                                                    \
  {                                                                          \
    const float4* xp = (const float4*)RSLOT((T_IDX) + 1);                    \
    _Pragma("unroll")                                                        \
    for (int q = 0; q < 16; ++q) X[q] = xp[q];                               \
    const int t2 = ((T_IDX) + 2 < LL) ? (T_IDX) + 2 : LL - 1;                \
    const float scp = RSLOT(t2)[lane];                                       \
    const float kkp = kkl[t2];                                               \
    const float vp = (vpA.x + vpA.y) + (vpB.x + vpB.y);                      \
    const float dv = sc - vp / (kk + 1e-6f);                                 \
    const float aa = dv * (2.f * vp + dv * kk);                              \
    const float s = wave_sum_dpp(aa);                                        \
    const float dvg = s > 0.f ? dv : 0.f;                                    \
    wcount += s > 0.f ? 1.f : 0.f;                                           \
    const v2f dv2 = (v2f){dvg, dvg};                                         \
    v2f nA = (v2f){0.f, 0.f}, nB = (v2f){0.f, 0.f};                          \
    _Pragma("unroll")                                                        \
    for (int q = 0; q < 16; ++q) {                                           \
      const float4 kv4 = R[q];                                               \
      const float4 kn4 = X[q];                                               \
      const v2f kva = (v2f){kv4.x, kv4.y}, kvb = (v2f){kv4.z, kv4.w};        \
      const v2f kna = (v2f){kn4.x, kn4.y}, knb = (v2f){kn4.z, kn4.w};        \
      M2[2 * q]     = __builtin_elementwise_fma(dv2, kva, M2[2 * q]);        \
      M2[2 * q + 1] = __builtin_elementwise_fma(dv2, kvb, M2[2 * q + 1]);    \
      nA = __builtin_elementwise_fma(M2[2 * q],     kna, nA);                \
      nB = __builtin_elementwise_fma(M2[2 * q + 1], knb, nB);                \
    }                                                                        \
    vpA = nA; vpB = nB;                                                      \
    sc = scn; kk = kkn; scn = scp; kkn = kkp;                                \
  }

// Phase 2+3 (DMA-ring): one block = one wave = one batch. Rows stream
// global->LDS ring via global_load_lds issued 8 rows ahead (1 instr / 4
// steps), counted vmcnt(1) wait per group. No data-dependent addresses, no
// global latency on the recurrence chain.
__global__ __launch_bounds__(64, 1) void scan_kernel_ring(
    const float* __restrict__ rows, const float* __restrict__ kks,
    const float* __restrict__ Wr, const float* __restrict__ br,
    const float* __restrict__ Wo, const float* __restrict__ bo,
    float* __restrict__ out, float* __restrict__ counts) {
  const int b = blockIdx.x;
  const int lane = threadIdx.x;
  const float* rb = rows + (long)b * LL * H;
  const float* kb = kks + (long)b * LL;
  __shared__ float ring[16 * H];   // 4 KB: 4 quarters x 4 rows x 64 f32
  __shared__ float dummy[4 * H];   // 1 KB: DMA target for tail groups
  __shared__ float kkl[LL];        // 8 KB: k.k per step
  __shared__ float xv[H];

  // Stage kk stream into LDS (one-time, compiler-managed waits).
  {
    const float4* ks = (const float4*)kb;
    float4* kd = (float4*)kkl;
#pragma unroll
    for (int q = 0; q < 8; ++q) kd[q * 64 + lane] = ks[q * 64 + lane];
  }
  // Prologue DMA: quarters 0,1 <- rows 0..7.
  dma16(rb + 0 * H + lane * 4, ring + 0 * 256);
  dma16(rb + 4 * H + lane * 4, ring + 1 * 256);
  __builtin_amdgcn_sched_barrier(0);
  asm volatile("s_waitcnt vmcnt(0) lgkmcnt(0)" ::: "memory");
  __builtin_amdgcn_sched_barrier(0);

  v2f M2[32];
#pragma unroll
  for (int r = 0; r < 32; ++r) M2[r] = (v2f){0.f, 0.f};
  float wcount = 0.f;

  float4 RA[16], RB[16];
  {
    const float4* r0 = (const float4*)ring;  // row 0
#pragma unroll
    for (int q = 0; q < 16; ++q) RA[q] = r0[q];
  }
  float sc = ring[lane], kk = kkl[0];
  float scn = ring[H + lane], kkn = kkl[1];
  v2f vpA = (v2f){0.f, 0.f}, vpB = (v2f){0.f, 0.f};  // M=0 -> vp(0)=0

  // 511 full groups of 4 steps + tail group of 3 = 2047 steps (t=0..2046).
  int t = 0;
  for (int g = 0; g < 511; ++g) {
    // DMA rows t+8..t+11 into quarter ((t/4)+2)&3; tail-clamped source goes
    // to the dummy slot (keeps vmcnt count uniform, never hits live quarters).
    const int srow = (t + 8 <= LL - 4) ? t + 8 : LL - 4;
    float* dst = (t + 8 <= LL - 4) ? (ring + (((t >> 2) + 2) & 3) * 256) : dummy;
    dma16(rb + (long)srow * H + lane * 4, dst);
    __builtin_amdgcn_sched_barrier(0);
    asm volatile("s_waitcnt vmcnt(1)" ::: "memory");  // rows..t+7 resident
    __builtin_amdgcn_sched_barrier(0);
    STEP(t, RA, RB); ++t;
    STEP(t, RB, RA); ++t;
    STEP(t, RA, RB); ++t;
    STEP(t, RB, RA); ++t;
  }
  {
    dma16(rb + (long)(LL - 4) * H + lane * 4, dummy);
    __builtin_amdgcn_sched_barrier(0);
    asm volatile("s_waitcnt vmcnt(1)" ::: "memory");
    __builtin_amdgcn_sched_barrier(0);
    STEP(t, RA, RB); ++t;   // 2044
    STEP(t, RB, RA); ++t;   // 2045
    STEP(t, RA, RB);        // 2046; dot row = stream row 2047
  }
  asm volatile("s_waitcnt vmcnt(0)" ::: "memory");

  xv[lane] = (vpA.x + vpA.y) + (vpB.x + vpB.y);
  __syncthreads();
  float t1 = br[lane];
#pragma unroll 8
  for (int i = 0; i < H; ++i) t1 = fmaf(xv[i], Wr[i * H + lane], t1);
  __syncthreads();
  xv[lane] = t1;
  __syncthreads();
  float lg = bo[lane];
#pragma unroll 8
  for (int m = 0; m < H; ++m) lg = fmaf(xv[m], Wo[m * H + lane], lg);
  out[(long)b * H + lane] = lg;
  if (lane == 0) counts[b] = wcount;
}

// ---------- Fallback (round-5 kernel, used only if ws too small) ----------
#define STEPL(T_IDX, RU, RD, RP)                                             \
  {                                                                          \
    const int cp = cnn;                                                      \
    const int tpre = ((T_IDX) + 3 < LL) ? (T_IDX) + 3 : LL - 1;              \
    int cin = toks[tpre];                                                    \
    float scp = T[cp * H + lane];                                            \
    float kkp = KK[cp];                                                      \
    const float4* rp = (const float4*)(T + cp * H);                          \
    _Pragma("unroll")                                                        \
    for (int q = 0; q < 16; ++q) RP[q] = rp[q];                              \
    const float vp = (vpA.x + vpA.y) + (vpB.x + vpB.y);                      \
    const float dv = sc - vp / (kk + 1e-6f);                                 \
    const float aa = dv * (2.f * vp + dv * kk);                              \
    const float s = wave_sum_dpp(aa);                                        \
    const float dvg = s > 0.f ? dv : 0.f;                                    \
    wcount += s > 0.f ? 1.f : 0.f;                                           \
    const v2f dv2 = (v2f){dvg, dvg};                                         \
    v2f nA = (v2f){0.f, 0.f}, nB = (v2f){0.f, 0.f};                          \
    _Pragma("unroll")                                                        \
    for (int q = 0; q < 16; ++q) {                                           \
      const float4 kv4 = RU[q];                                              \
      const float4 kn4 = RD[q];                                              \
      const v2f kva = (v2f){kv4.x, kv4.y}, kvb = (v2f){kv4.z, kv4.w};        \
      const v2f kna = (v2f){kn4.x, kn4.y}, knb = (v2f){kn4.z, kn4.w};        \
      M2[2 * q]     = __builtin_elementwise_fma(dv2, kva, M2[2 * q]);        \
      M2[2 * q + 1] = __builtin_elementwise_fma(dv2, kvb, M2[2 * q + 1]);    \
      nA = __builtin_elementwise_fma(M2[2 * q],     kna, nA);                \
      nB = __builtin_elementwise_fma(M2[2 * q + 1], knb, nB);                \
    }                                                                        \
    vpA = nA; vpB = nB;                                                      \
    _Pragma("unroll")                                                        \
    for (int q = 0; q < 16; ++q) PIN4(RP[q]);                                \
    PIN(scp); PIN(kkp); PIN(cin);                                            \
    cn = cnn; cnn = cin;                                                     \
    sc = scn; kk = kkn; scn = scp; kkn = kkp;                                \
  }

__global__ __launch_bounds__(64, 1) void scan_kernel_lds(
    const int* __restrict__ seq, const float* __restrict__ table,
    const float* __restrict__ kkg, const float* __restrict__ Wr,
    const float* __restrict__ br, const float* __restrict__ Wo,
    const float* __restrict__ bo, float* __restrict__ out,
    float* __restrict__ counts) {
  const int b = blockIdx.x;
  const int lane = threadIdx.x;
  __shared__ float T[H * VOCAB];
  __shared__ float KK[VOCAB];
  __shared__ int toks[LL];
  __shared__ float xv[H];
  {
    const float4* src = (const float4*)table;
    float4* dst = (float4*)T;
#pragma unroll
    for (int q = 0; q < 16; ++q) dst[q * 64 + lane] = src[q * 64 + lane];
    KK[lane] = kkg[lane];
    const int4* ssrc = (const int4*)(seq + (long)b * LL);
    int4* sdst = (int4*)toks;
#pragma unroll
    for (int q = 0; q < 8; ++q) sdst[q * 64 + lane] = ssrc[q * 64 + lane];
  }
  __syncthreads();
  v2f M2[32];
#pragma unroll
  for (int r = 0; r < 32; ++r) M2[r] = (v2f){0.f, 0.f};
  float wcount = 0.f;
  float4 RA[16], RB[16], RC[16];
  const int c0 = toks[0];
  int cn = toks[1], cnn = toks[2];
  float sc = T[c0 * H + lane], kk = KK[c0];
  float scn = T[cn * H + lane], kkn = KK[cn];
  {
    const float4* r0 = (const float4*)(T + c0 * H);
    const float4* r1 = (const float4*)(T + cn * H);
#pragma unroll
    for (int q = 0; q < 16; ++q) { RA[q] = r0[q]; RB[q] = r1[q]; }
#pragma unroll
    for (int q = 0; q < 16; ++q) { PIN4(RA[q]); PIN4(RB[q]); }
  }
  v2f vpA = (v2f){0.f, 0.f}, vpB = (v2f){0.f, 0.f};
  int t = 0;
  for (int it = 0; it < 682; ++it) {
    STEPL(t, RA, RB, RC); ++t;
    STEPL(t, RB, RC, RA); ++t;
    STEPL(t, RC, RA, RB); ++t;
  }
  STEPL(t, RA, RB, RC);
  xv[lane] = (vpA.x + vpA.y) + (vpB.x + vpB.y);
  __syncthreads();
  float t1 = br[lane];
#pragma unroll 8
  for (int i = 0; i < H; ++i) t1 = fmaf(xv[i], Wr[i * H + lane], t1);
  __syncthreads();
  xv[lane] = t1;
  __syncthreads();
  float lg = bo[lane];
#pragma unroll 8
  for (int m = 0; m < H; ++m) lg = fmaf(xv[m], Wo[m * H + lane], lg);
  out[(long)b * H + lane] = lg;
  if (lane == 0) counts[b] = wcount;
}

__global__ __launch_bounds__(256, 1) void finalize_kernel(const float* __restrict__ counts,
                                                          float* __restrict__ out) {
  const int lane = threadIdx.x;
  __shared__ float sbuf[BB];
  sbuf[lane] = counts[lane];
  __syncthreads();
  for (int off = BB / 2; off > 0; off >>= 1) {
    if (lane < off) sbuf[lane] += sbuf[lane + off];
    __syncthreads();
  }
  if (lane == 0) out[BB * H] = sbuf[0] / (float)(BB * (LL - 1));
}

extern "C" void kernel_launch(void* const* d_in, const int* in_sizes, int n_in,
                              void* d_out, int out_size, void* d_ws, size_t ws_size,
                              hipStream_t stream) {
  const int* seq      = (const int*)d_in[0];
  const float* embed  = (const float*)d_in[1];
  const float* W1     = (const float*)d_in[2];
  const float* b1     = (const float*)d_in[3];
  const float* W2     = (const float*)d_in[4];
  const float* b2     = (const float*)d_in[5];
  const float* gamma  = (const float*)d_in[6];
  const float* beta   = (const float*)d_in[7];
  const float* Wr     = (const float*)d_in[8];
  const float* br     = (const float*)d_in[9];
  const float* Wo     = (const float*)d_in[10];
  const float* bo     = (const float*)d_in[11];
  float* out = (float*)d_out;

  float* ws = (float*)d_ws;
  float* table  = ws;                    // 4096 f32
  float* kkg    = table + VOCAB * H;     // 64 f32
  float* counts = kkg + VOCAB;           // 256 f32
  float* rows   = ws + 8192;             // BB*LL*H f32 = 134 MB
  float* kks    = rows + (size_t)BB * LL * H;  // BB*LL f32 = 2 MB
  const size_t need = (8192 + (size_t)BB * LL * H + (size_t)BB * LL) * sizeof(float);

  encode_kernel<<<VOCAB, H, 0, stream>>>(embed, W1, b1, W2, b2, gamma, beta, table, kkg);
  if (ws_size >= need) {
    gather_kernel<<<BB, 256, 0, stream>>>(seq, table, kkg, rows, kks);
    scan_kernel_ring<<<BB, H, 0, stream>>>(rows, kks, Wr, br, Wo, bo, out, counts);
  } else {
    scan_kernel_lds<<<BB, H, 0, stream>>>(seq, table, kkg, Wr, br, Wo, bo, out, counts);
  }
  finalize_kernel<<<1, BB, 0, stream>>>(counts, out);
}